// Round 8
// baseline (25.696 us; speedup 1.0000x reference)
//
#include <hip/hip_runtime.h>

#define RES 128
#define NB 16
#define NPTS (RES * RES)

typedef __attribute__((ext_vector_type(2))) float f32x2;

// exp(i*2*pi*rev) via hardware v_sin/v_cos (operand in revolutions, fract-reduced)
__device__ __forceinline__ float2 cis_rev(float rev) {
    float r = __builtin_amdgcn_fractf(rev);
    return make_float2(__builtin_amdgcn_cosf(r), __builtin_amdgcn_sinf(r));
}

// Packed complex MAC: acc += (ux + i*uy) * v, with v = (v.x, v.y), vsw = (-v.y, v.x).
// Two v_pk_fma_f32 per call; vsw is built once per twiddle and shared across rows.
__device__ __forceinline__ void cmac_pk(f32x2& acc, float ux, float uy,
                                        f32x2 v, f32x2 vsw) {
    f32x2 ur = {ux, ux}, ui = {uy, uy};
    acc = __builtin_elementwise_fma(ur, v, acc);
    acc = __builtin_elementwise_fma(ui, vsw, acc);
}

// Column pass: T[b,i,w] = sum_j s[b,i,j] * exp(i*2pi/128 * b_j * (w-64))
// grid 256 = (b, 8-row i-slab), block 512; thread = (w = tid&127, g = tid>>7),
// accumulates rows i0+2g, i0+2g+1 (s-pair packed as float4 -> 1 LDS broadcast).
__global__ __launch_bounds__(512) void kB_colpass(
    const float* __restrict__ kin, const float* __restrict__ traj,
    float2* __restrict__ T)
{
    __shared__ float4 sSp[4][RES];        // 8 KB: sSp[p][j] = rows (2p, 2p+1) at j
    __shared__ float2 FyT[2][32][RES];    // 64 KB double-buffered twiddle tiles
    __shared__ float  bjS[RES];           // column coords b_j
    const int b   = blockIdx.x >> 4;
    const int i0  = (blockIdx.x & 15) * 8;
    const int tid = threadIdx.x;
    const int w   = tid & (RES - 1);
    const int g   = tid >> 7;                        // 0..3, wave-uniform

    const float2* img = (const float2*)kin + b * NPTS;   // [H][W] complex
    const float2* tp  = (const float2*)traj;             // [M] (row, col)

    if (tid < RES) bjS[tid] = tp[tid].y;

    // ---- bilinear-sample 8 trajectory rows (1024 pts, 2/thread)
    #pragma unroll
    for (int k = 0; k < 2; ++k) {
        int idx = tid + k * 512;                     // [0,1024)
        int ii = idx >> 7;                           // 0..7
        int j  = idx & (RES - 1);
        float2 t2 = tp[(i0 + ii) * RES + j];
        float pr = t2.x + 64.f, pc = t2.y + 64.f;
        float r0f = floorf(pr), c0f = floorf(pc);
        float wr = pr - r0f, wc = pc - c0f;
        int r0 = min(max((int)r0f, 0), RES - 1);
        int r1 = min(r0 + 1, RES - 1);
        int c0 = min(max((int)c0f, 0), RES - 1);
        int c1 = min(c0 + 1, RES - 1);
        float2 g00 = img[r0 * RES + c0], g01 = img[r0 * RES + c1];
        float2 g10 = img[r1 * RES + c0], g11 = img[r1 * RES + c1];
        float w00 = (1.f - wr) * (1.f - wc), w01 = (1.f - wr) * wc;
        float w10 = wr * (1.f - wc),         w11 = wr * wc;
        float2* dst = (float2*)&sSp[ii >> 1][j] + (ii & 1);
        *dst = make_float2(
            w00 * g00.x + w01 * g01.x + w10 * g10.x + w11 * g11.x,
            w00 * g00.y + w01 * g01.y + w10 * g10.y + w11 * g11.y);
    }
    __syncthreads();

    const float wf = (float)(w - 64) * 0.0078125f;   // (w-64)/128

    // gen tile t into buffer bf: rows [8g, 8g+8) of the 32-row tile, lane-consec writes
    auto gen = [&](int t, int bf) {
        #pragma unroll
        for (int q = 0; q < 8; ++q) {
            float bj = bjS[32 * t + 8 * g + q];      // broadcast
            FyT[bf][8 * g + q][w] = cis_rev(bj * wf);
        }
    };

    gen(0, 0);
    __syncthreads();

    f32x2 a0 = {0.f, 0.f}, a1 = {0.f, 0.f};
    for (int t = 0; t < 4; ++t) {
        if (t < 3) gen(t + 1, (t + 1) & 1);
        #pragma unroll 8
        for (int jj = 0; jj < 32; ++jj) {
            float2 fy = FyT[t & 1][jj][w];           // lane-consecutive b64
            f32x2 v   = {fy.x, fy.y};
            f32x2 vsw = {-fy.y, fy.x};               // shared across both rows
            float4 sp = sSp[g][32 * t + jj];         // wave-uniform b128 broadcast
            cmac_pk(a0, sp.x, sp.y, v, vsw);
            cmac_pk(a1, sp.z, sp.w, v, vsw);
        }
        if (t < 3) __syncthreads();
    }

    T[(b * RES + i0 + 2 * g + 0) * RES + w] = make_float2(a0.x, a0.y);
    T[(b * RES + i0 + 2 * g + 1) * RES + w] = make_float2(a1.x, a1.y);
}

// Row pass: out[b,h,w] = sum_i exp(i*2pi/128 * a_i * (h-64)) * T[b,i,w]
// grid 256 = (b, 8-row h-slab), block 512; thread = (w, g) -> rows h0+2g, h0+2g+1.
__global__ __launch_bounds__(512) void kC_rowpass(
    const float2* __restrict__ T, const float* __restrict__ traj,
    float* __restrict__ out)
{
    __shared__ float4 fSp[4][RES];        // 8 KB: fSp[p][i] = rows (2p, 2p+1) at i
    const int b   = blockIdx.x >> 4;
    const int h0  = (blockIdx.x & 15) * 8;
    const int tid = threadIdx.x;
    const int w   = tid & (RES - 1);
    const int g   = tid >> 7;                        // 0..3, wave-uniform

    const float2* tp = (const float2*)traj;

    // twiddles: 1024 entries, 2/thread, hw sincos in revolutions
    #pragma unroll
    for (int k = 0; k < 2; ++k) {
        int idx = tid + k * 512;                     // [0,1024)
        int hh = idx >> 7;                           // 0..7
        int i  = idx & (RES - 1);
        float ai = tp[i * RES].x;                    // row coord of point (i, 0)
        float2* dst = (float2*)&fSp[hh >> 1][i] + (hh & 1);
        *dst = cis_rev(ai * (float)(h0 + hh - 64) * 0.0078125f);
    }
    __syncthreads();

    const float2* Tb = T + b * NPTS;
    f32x2 b0 = {0.f, 0.f}, b1 = {0.f, 0.f};
    #pragma unroll 8
    for (int i = 0; i < RES; ++i) {
        float2 tv = Tb[i * RES + w];                 // coalesced b64, L2/L1-resident
        f32x2 v   = {tv.x, tv.y};
        f32x2 vsw = {-tv.y, tv.x};                   // shared across both rows
        float4 fp = fSp[g][i];                       // wave-uniform b128 broadcast
        cmac_pk(b0, fp.x, fp.y, v, vsw);
        cmac_pk(b1, fp.z, fp.w, v, vsw);
    }

    float* o = out + b * 2 * NPTS;
    int h = h0 + 2 * g;
    o[h * RES + w]              = b0.x;
    o[NPTS + h * RES + w]       = b0.y;
    o[(h + 1) * RES + w]        = b1.x;
    o[NPTS + (h + 1) * RES + w] = b1.y;
}

extern "C" void kernel_launch(void* const* d_in, const int* in_sizes, int n_in,
                              void* d_out, int out_size, void* d_ws, size_t ws_size,
                              hipStream_t stream) {
    const float* kin  = (const float*)d_in[0];   // [16,1,128,128,2] f32
    const float* traj = (const float*)d_in[1];   // [16384,2] f32
    float* out = (float*)d_out;                  // [16,1,2,128,128] f32
    float2* T = (float2*)d_ws;                   // NB*NPTS float2

    kB_colpass<<<NB * (RES / 8), 512, 0, stream>>>(kin, traj, T);
    kC_rowpass<<<NB * (RES / 8), 512, 0, stream>>>(T, traj, out);
}

// Round 9
// 24.745 us; speedup vs baseline: 1.0384x; 1.0384x over previous
//
#include <hip/hip_runtime.h>

#define RES 128
#define NB 16
#define NPTS (RES * RES)

__device__ __forceinline__ void cmac(float2& a, float2 u, float2 v) {
    a.x = fmaf(u.x, v.x, fmaf(-u.y, v.y, a.x));
    a.y = fmaf(u.x, v.y, fmaf( u.y, v.x, a.y));
}

// exp(i*2*pi*rev) via hardware v_sin/v_cos (operand in revolutions, fract-reduced)
__device__ __forceinline__ float2 cis_rev(float rev) {
    float r = __builtin_amdgcn_fractf(rev);
    return make_float2(__builtin_amdgcn_cosf(r), __builtin_amdgcn_sinf(r));
}

// Column pass: T[b,i,w] = sum_j s[b,i,j] * exp(i*2pi/128 * b_j * (w-64))
// grid 256 = (b, 8-row i-slab), block 512; thread = (w = tid&127, g = tid>>7),
// accumulates rows i0+2g, i0+2g+1 (s-pair packed as float4 -> 1 LDS broadcast).
__global__ __launch_bounds__(512) void kB_colpass(
    const float* __restrict__ kin, const float* __restrict__ traj,
    float2* __restrict__ T)
{
    __shared__ float4 sSp[4][RES];        // 8 KB: sSp[p][j] = rows (2p, 2p+1) at j
    __shared__ float2 FyT[2][32][RES];    // 64 KB double-buffered twiddle tiles
    __shared__ float  bjS[RES];           // column coords b_j
    const int b   = blockIdx.x >> 4;
    const int i0  = (blockIdx.x & 15) * 8;
    const int tid = threadIdx.x;
    const int w   = tid & (RES - 1);
    const int g   = tid >> 7;                        // 0..3, wave-uniform

    const float2* img = (const float2*)kin + b * NPTS;   // [H][W] complex
    const float2* tp  = (const float2*)traj;             // [M] (row, col)

    if (tid < RES) bjS[tid] = tp[tid].y;

    // ---- bilinear-sample 8 trajectory rows (1024 pts, 2/thread)
    #pragma unroll
    for (int k = 0; k < 2; ++k) {
        int idx = tid + k * 512;                     // [0,1024)
        int ii = idx >> 7;                           // 0..7
        int j  = idx & (RES - 1);
        float2 t2 = tp[(i0 + ii) * RES + j];
        float pr = t2.x + 64.f, pc = t2.y + 64.f;
        float r0f = floorf(pr), c0f = floorf(pc);
        float wr = pr - r0f, wc = pc - c0f;
        int r0 = min(max((int)r0f, 0), RES - 1);
        int r1 = min(r0 + 1, RES - 1);
        int c0 = min(max((int)c0f, 0), RES - 1);
        int c1 = min(c0 + 1, RES - 1);
        float2 g00 = img[r0 * RES + c0], g01 = img[r0 * RES + c1];
        float2 g10 = img[r1 * RES + c0], g11 = img[r1 * RES + c1];
        float w00 = (1.f - wr) * (1.f - wc), w01 = (1.f - wr) * wc;
        float w10 = wr * (1.f - wc),         w11 = wr * wc;
        float2* dst = (float2*)&sSp[ii >> 1][j] + (ii & 1);
        *dst = make_float2(
            w00 * g00.x + w01 * g01.x + w10 * g10.x + w11 * g11.x,
            w00 * g00.y + w01 * g01.y + w10 * g10.y + w11 * g11.y);
    }
    __syncthreads();

    const float wf = (float)(w - 64) * 0.0078125f;   // (w-64)/128

    // gen tile t into buffer bf: rows [8g, 8g+8) of the 32-row tile, lane-consec writes
    auto gen = [&](int t, int bf) {
        #pragma unroll
        for (int q = 0; q < 8; ++q) {
            float bj = bjS[32 * t + 8 * g + q];      // broadcast
            FyT[bf][8 * g + q][w] = cis_rev(bj * wf);
        }
    };

    gen(0, 0);
    __syncthreads();

    float2 a0 = make_float2(0.f, 0.f), a1 = make_float2(0.f, 0.f);
    for (int t = 0; t < 4; ++t) {
        if (t < 3) gen(t + 1, (t + 1) & 1);
        #pragma unroll 8
        for (int jj = 0; jj < 32; ++jj) {
            float2 fy = FyT[t & 1][jj][w];           // lane-consecutive b64
            float4 sp = sSp[g][32 * t + jj];         // wave-uniform b128 broadcast
            cmac(a0, make_float2(sp.x, sp.y), fy);
            cmac(a1, make_float2(sp.z, sp.w), fy);
        }
        if (t < 3) __syncthreads();
    }

    T[(b * RES + i0 + 2 * g + 0) * RES + w] = a0;
    T[(b * RES + i0 + 2 * g + 1) * RES + w] = a1;
}

// Row pass: out[b,h,w] = sum_i exp(i*2pi/128 * a_i * (h-64)) * T[b,i,w]
// grid 256 = (b, 8-row h-slab), block 512; thread = (w, g) -> rows h0+2g, h0+2g+1.
__global__ __launch_bounds__(512) void kC_rowpass(
    const float2* __restrict__ T, const float* __restrict__ traj,
    float* __restrict__ out)
{
    __shared__ float4 fSp[4][RES];        // 8 KB: fSp[p][i] = rows (2p, 2p+1) at i
    const int b   = blockIdx.x >> 4;
    const int h0  = (blockIdx.x & 15) * 8;
    const int tid = threadIdx.x;
    const int w   = tid & (RES - 1);
    const int g   = tid >> 7;                        // 0..3, wave-uniform

    const float2* tp = (const float2*)traj;

    // twiddles: 1024 entries, 2/thread, hw sincos in revolutions
    #pragma unroll
    for (int k = 0; k < 2; ++k) {
        int idx = tid + k * 512;                     // [0,1024)
        int hh = idx >> 7;                           // 0..7
        int i  = idx & (RES - 1);
        float ai = tp[i * RES].x;                    // row coord of point (i, 0)
        float2* dst = (float2*)&fSp[hh >> 1][i] + (hh & 1);
        *dst = cis_rev(ai * (float)(h0 + hh - 64) * 0.0078125f);
    }
    __syncthreads();

    const float2* Tb = T + b * NPTS;
    float2 b0 = make_float2(0.f, 0.f), b1 = make_float2(0.f, 0.f);
    #pragma unroll 8
    for (int i = 0; i < RES; ++i) {
        float2 tv = Tb[i * RES + w];                 // coalesced b64, L2-resident
        float4 fp = fSp[g][i];                       // wave-uniform b128 broadcast
        cmac(b0, make_float2(fp.x, fp.y), tv);
        cmac(b1, make_float2(fp.z, fp.w), tv);
    }

    float* o = out + b * 2 * NPTS;
    int h = h0 + 2 * g;
    o[h * RES + w]              = b0.x;
    o[NPTS + h * RES + w]       = b0.y;
    o[(h + 1) * RES + w]        = b1.x;
    o[NPTS + (h + 1) * RES + w] = b1.y;
}

extern "C" void kernel_launch(void* const* d_in, const int* in_sizes, int n_in,
                              void* d_out, int out_size, void* d_ws, size_t ws_size,
                              hipStream_t stream) {
    const float* kin  = (const float*)d_in[0];   // [16,1,128,128,2] f32
    const float* traj = (const float*)d_in[1];   // [16384,2] f32
    float* out = (float*)d_out;                  // [16,1,2,128,128] f32
    float2* T = (float2*)d_ws;                   // NB*NPTS float2

    kB_colpass<<<NB * (RES / 8), 512, 0, stream>>>(kin, traj, T);
    kC_rowpass<<<NB * (RES / 8), 512, 0, stream>>>(T, traj, out);
}